// Round 9
// baseline (1481.319 us; speedup 1.0000x reference)
//
#include <hip/hip_runtime.h>
#include <hip/hip_fp16.h>

#define NN 100000      // nodes graph 1
#define MMn 200000     // nodes graph 2 (link nodes)
#define DD 64
#define NE1 3200000
#define NE2 3200000
#define SHB 6          // 64-node buckets
#define NB1 1563       // ceil(NN/64)
#define NB2 3125       // MMn/64
#define CAP1 2560      // g1 bucket capacity: mean 2048 + ~11 sigma
#define CAP2 1536      // g2 bucket capacity: mean 1024 + ~16 sigma
#define NBLK 256       // staging blocks
#define GGRID 2048     // grid-stride blocks for gcn kernels

static inline int cdiv_l(long a, long b) { return (int)((a + b - 1) / b); }

// ================= small utility kernels =================
__global__ void fill_i32_k(int* p, int v, long n) {
    long i = (long)blockIdx.x * blockDim.x + threadIdx.x;
    long st = (long)gridDim.x * blockDim.x;
    for (; i < n; i += st) p[i] = v;
}
__global__ void fill_f32_k(float* p, float v, long n) {
    long i = (long)blockIdx.x * blockDim.x + threadIdx.x;
    long st = (long)gridDim.x * blockDim.x;
    for (; i < n; i += st) p[i] = v;
}
__global__ void ginit_k(int* gcur, int nb, int cap) {
    int b = blockIdx.x * blockDim.x + threadIdx.x;
    if (b < nb) gcur[b] = b * cap;
}
__global__ void histx_k(const int* __restrict__ x, int n, int* __restrict__ freq) {
    int i = blockIdx.x * blockDim.x + threadIdx.x;
    if (i < n) atomicAdd(&freq[x[i]], 1);
}

// ================= atomic-light bucketed staging; packed entry = (val<<6)|(key&63) =================
__global__ __launch_bounds__(256) void stage_one_k(
    const int* __restrict__ keys, const int* __restrict__ vals, int ne,
    int* __restrict__ gcur, int* __restrict__ stg, int nb, int cap)
{
    __shared__ int lcnt[3200];
    __shared__ int lbase[3200];
    int tid = threadIdx.x;
    for (int b = tid; b < nb; b += 256) lcnt[b] = 0;
    __syncthreads();
    int chunk = (ne + (int)gridDim.x - 1) / (int)gridDim.x;
    int s = blockIdx.x * chunk, e = min(ne, s + chunk);
    for (int i = s + tid; i < e; i += 256) atomicAdd(&lcnt[keys[i] >> SHB], 1);
    __syncthreads();
    for (int b = tid; b < nb; b += 256) {
        int c = lcnt[b];
        lbase[b] = c ? atomicAdd(&gcur[b], c) : 0;
        lcnt[b] = 0;
    }
    __syncthreads();
    for (int i = s + tid; i < e; i += 256) {
        int k = keys[i];
        int bkt = k >> SHB;
        int idx = atomicAdd(&lcnt[bkt], 1);   // LDS cursor
        long pos = (long)lbase[bkt] + idx;
        if (pos < (long)(bkt + 1) * cap) stg[pos] = (vals[i] << 6) | (k & 63);
    }
}

// ================= bucket-local CSR fill: zero global atomics =================
template <int CAPT>
__global__ __launch_bounds__(256) void fill_one_k(
    const int* __restrict__ stg, const int* __restrict__ gcur, int n,
    int* __restrict__ rows, int2* __restrict__ offs, float* __restrict__ dinv)
{
    __shared__ int ent[CAPT];
    __shared__ int deg[64];
    __shared__ int sstart[65];
    int b = blockIdx.x, tid = threadIdx.x;
    long s = (long)b * CAPT;
    int cnt = min(gcur[b] - (int)s, CAPT);
    if (tid < 64) deg[tid] = 0;
    __syncthreads();
    for (int i = tid; i < cnt; i += 256) {
        int u = stg[s + i];
        ent[i] = u;
        atomicAdd(&deg[u & 63], 1);
    }
    __syncthreads();
    if (tid == 0) {
        int acc = 0;
#pragma unroll
        for (int j = 0; j < 64; ++j) { sstart[j] = acc; acc += deg[j]; }
        sstart[64] = acc;
    }
    __syncthreads();
    int node = (b << SHB) + tid;
    if (tid < 64 && node < n) {
        int st = sstart[tid], en = sstart[tid + 1];
        offs[node] = make_int2((int)s + st, (int)s + en);
        dinv[node] = rsqrtf((float)(en - st) + 1.0f);
    }
    if (tid < 64) deg[tid] = sstart[tid];  // reuse as cursor
    __syncthreads();
    for (int i = tid; i < cnt; i += 256) {
        int u = ent[i];
        int idx = atomicAdd(&deg[u & 63], 1);   // LDS cursor
        rows[s + idx] = ((unsigned)u) >> 6;
    }
}

// ================= GraphNorm coefficient (inline, per consumer) =================
__device__ __forceinline__ void gn_coef(const float* __restrict__ stats,
                                        const float* __restrict__ w, const float* __restrict__ b,
                                        const float* __restrict__ ms, float nrows, int d,
                                        float& sc, float& sh) {
    float mean = stats[d] / nrows;
    float ex2 = stats[64 + d] / nrows;
    float m = ms[d];
    float var = ex2 - mean * mean * (2.f * m - m * m);
    float is = rsqrtf(var + 1e-5f);
    sc = is * w[d];
    sh = b[d] - m * mean * sc;
}

// ================= embedding-table stats (frequency-weighted moments) =================
__global__ __launch_bounds__(256) void tabstats_k(const float* __restrict__ T, const int* __restrict__ freq,
                                                  int nv, float* __restrict__ stats) {
    __shared__ float sS[256], sQ[256];
    int tid = threadIdx.x; int d = tid & 63; int g = tid >> 6;
    float s = 0.f, q = 0.f;
    for (int v = g; v < nv; v += 4) {
        float f = (float)freq[v];
        float t = T[(long)v * DD + d];
        s += f * t; q += f * t * t;
    }
    sS[tid] = s; sQ[tid] = q; __syncthreads();
    if (tid < 128) { sS[tid] += sS[tid + 128]; sQ[tid] += sQ[tid + 128]; }
    __syncthreads();
    if (tid < 64) { stats[d] = sS[tid] + sS[tid + 64]; stats[64 + d] = sQ[tid] + sQ[tid + 64]; }
}

// ================= normalized fp16 embedding table =================
__global__ void tnorm_k(const float* __restrict__ T, const float* __restrict__ stats,
                        const float* __restrict__ w, const float* __restrict__ b,
                        const float* __restrict__ ms, __half* __restrict__ Tn, int nv) {
    int i = blockIdx.x * blockDim.x + threadIdx.x;
    if (i >= nv * DD) return;
    int d = i & 63;
    float sc, sh;
    gn_coef(stats, w, b, ms, (float)NN, d, sc, sh);
    Tn[i] = __float2half(fmaf(T[i], sc, sh));
}

// load W (row-major [k][d]) into LDS as float4 chunks: sW4[j*64+d] = W[4j..4j+3][d]
__device__ __forceinline__ void load_W4(const float* __restrict__ W, float4* sW4, int tid) {
    for (int idx = tid; idx < 1024; idx += 256) {
        int j = idx >> 6, dd = idx & 63;
        int k = j * 4;
        sW4[idx] = make_float4(W[k * 64 + dd], W[(k + 1) * 64 + dd],
                               W[(k + 2) * 64 + dd], W[(k + 3) * 64 + dd]);
    }
}

// ================= conv2 gather: pre-scaled input -> pure sum + matmul + stats =================
// Input hsrc is ALREADY h*dinv (per-row). P[c] = (sum_r hsrc[r] + hsrc[c]) * dinv[c].
// No per-edge weight: chain is rows[i] -> h2[r] -> add. 8 edges/group in flight.
__global__ __launch_bounds__(256) void gcn_sum_k(
    const __half* __restrict__ hsrc, const int2* __restrict__ offs,
    const int* __restrict__ rows, const float* __restrict__ dinv,
    const float* __restrict__ W, const float* __restrict__ bias,
    __half* __restrict__ Z, float* __restrict__ ostats, int n)
{
    __shared__ float4 sW4[1024];
    __shared__ float sP[256];
    __shared__ float rs[256];
    int tid = threadIdx.x;
    load_W4(W, sW4, tid);
    int wr = tid >> 6, d = tid & 63;
    int q = tid & 31, grp = (tid >> 5) & 1;
    float bd = bias[d];
    float sumz = 0.f, sumq = 0.f;
    const __half2* h2 = (const __half2*)hsrc;
    float2* sPw = (float2*)(sP + wr * 64);
    const float4* sPv = (const float4*)(sP + wr * 64);
    int ngrp = (n + 3) >> 2;
    __syncthreads();   // sW4 ready; no barriers inside the loop
    for (int g = blockIdx.x; g < ngrp; g += gridDim.x) {
        int node = g * 4 + wr;
        if (node < n) {
            int2 se = offs[node];
            int s = se.x, e = se.y;
            float dc = dinv[node];
            float a0 = 0.f, a1 = 0.f, b0 = 0.f, b1 = 0.f;
            float c0 = 0.f, c1 = 0.f, e0 = 0.f, e1 = 0.f;
            if (!grp) {
                __half2 u = h2[(long)node * 32 + q];   // self term (pre-scaled)
                a0 = __low2float(u); a1 = __high2float(u);
            }
            int i = s + grp;
            for (; i + 14 < e; i += 16) {
                int r0 = rows[i],      r1 = rows[i + 2],  r2 = rows[i + 4],  r3 = rows[i + 6];
                int r4 = rows[i + 8],  r5 = rows[i + 10], r6 = rows[i + 12], r7 = rows[i + 14];
                __half2 u0 = h2[(long)r0 * 32 + q];
                __half2 u1 = h2[(long)r1 * 32 + q];
                __half2 u2 = h2[(long)r2 * 32 + q];
                __half2 u3 = h2[(long)r3 * 32 + q];
                __half2 u4 = h2[(long)r4 * 32 + q];
                __half2 u5 = h2[(long)r5 * 32 + q];
                __half2 u6 = h2[(long)r6 * 32 + q];
                __half2 u7 = h2[(long)r7 * 32 + q];
                a0 += __low2float(u0); a1 += __high2float(u0);
                b0 += __low2float(u1); b1 += __high2float(u1);
                c0 += __low2float(u2); c1 += __high2float(u2);
                e0 += __low2float(u3); e1 += __high2float(u3);
                a0 += __low2float(u4); a1 += __high2float(u4);
                b0 += __low2float(u5); b1 += __high2float(u5);
                c0 += __low2float(u6); c1 += __high2float(u6);
                e0 += __low2float(u7); e1 += __high2float(u7);
            }
            for (; i < e; i += 2) {
                __half2 u = h2[(long)rows[i] * 32 + q];
                a0 += __low2float(u); a1 += __high2float(u);
            }
            a0 = (a0 + b0) + (c0 + e0);
            a1 = (a1 + b1) + (c1 + e1);
            a0 += __shfl_xor(a0, 32, 64);
            a1 += __shfl_xor(a1, 32, 64);
            if (!grp) sPw[q] = make_float2(a0 * dc, a1 * dc);  // wave-private slice
            float z = bd;
#pragma unroll
            for (int j = 0; j < 16; ++j) {
                float4 pv = sPv[j];
                float4 wv = sW4[j * 64 + d];
                z = fmaf(pv.x, wv.x, z); z = fmaf(pv.y, wv.y, z);
                z = fmaf(pv.z, wv.z, z); z = fmaf(pv.w, wv.w, z);
            }
            Z[(long)node * DD + d] = __float2half(z);
            sumz += z; sumq += z * z;
        }
    }
    __syncthreads();
    rs[tid] = sumz; __syncthreads();
    if (tid < 64) atomicAdd(&ostats[tid], rs[tid] + rs[tid + 64] + rs[tid + 128] + rs[tid + 192]);
    __syncthreads();
    rs[tid] = sumq; __syncthreads();
    if (tid < 64) atomicAdd(&ostats[64 + tid], rs[tid] + rs[tid + 64] + rs[tid + 128] + rs[tid + 192]);
}

// ================= conv1 l1: half2 gather with norm+relu on reads (keeps dinv path) =================
__global__ __launch_bounds__(256) void gcn_fused_k(
    const __half* __restrict__ hsrc, const int2* __restrict__ offs,
    const int* __restrict__ rows, const float* __restrict__ dinv,
    const float* __restrict__ stats, const float* __restrict__ gw,
    const float* __restrict__ gb, const float* __restrict__ gms, float nprev,
    const float* __restrict__ W, const float* __restrict__ bias,
    __half* __restrict__ Z, float* __restrict__ ostats, int n)
{
    __shared__ float4 sW4[1024];
    __shared__ float sP[256];
    __shared__ float rs[256];
    int tid = threadIdx.x;
    load_W4(W, sW4, tid);
    int wr = tid >> 6, d = tid & 63;
    int q = tid & 31, grp = (tid >> 5) & 1;
    int d0 = q * 2;
    float sc0, sh0, sc1, sh1;
    gn_coef(stats, gw, gb, gms, nprev, d0, sc0, sh0);
    gn_coef(stats, gw, gb, gms, nprev, d0 + 1, sc1, sh1);
    float bd = bias[d];
    float sumz = 0.f, sumq = 0.f;
    const __half2* h2 = (const __half2*)hsrc;
    float2* sPw = (float2*)(sP + wr * 64);
    const float4* sPv = (const float4*)(sP + wr * 64);
    int ngrp = (n + 3) >> 2;
    __syncthreads();
    for (int g = blockIdx.x; g < ngrp; g += gridDim.x) {
        int node = g * 4 + wr;
        if (node < n) {
            int2 se = offs[node];
            int s = se.x, e = se.y;
            float dc = dinv[node];
            float a0 = 0.f, a1 = 0.f, b0 = 0.f, b1 = 0.f;
            float c0 = 0.f, c1 = 0.f, e0 = 0.f, e1 = 0.f;
            if (!grp) {
                __half2 u = h2[(long)node * 32 + q];
                float x0 = fmaxf(fmaf(__low2float(u), sc0, sh0), 0.f);
                float x1 = fmaxf(fmaf(__high2float(u), sc1, sh1), 0.f);
                a0 = x0 * dc; a1 = x1 * dc;
            }
            int i = s + grp;
            for (; i + 6 < e; i += 8) {
                int r0 = rows[i], r1 = rows[i + 2], r2 = rows[i + 4], r3 = rows[i + 6];
                float w0 = dinv[r0], w1 = dinv[r1], w2 = dinv[r2], w3 = dinv[r3];
                __half2 u0 = h2[(long)r0 * 32 + q];
                __half2 u1 = h2[(long)r1 * 32 + q];
                __half2 u2 = h2[(long)r2 * 32 + q];
                __half2 u3 = h2[(long)r3 * 32 + q];
                float x00 = fmaxf(fmaf(__low2float(u0), sc0, sh0), 0.f);
                float x01 = fmaxf(fmaf(__high2float(u0), sc1, sh1), 0.f);
                float x10 = fmaxf(fmaf(__low2float(u1), sc0, sh0), 0.f);
                float x11 = fmaxf(fmaf(__high2float(u1), sc1, sh1), 0.f);
                float x20 = fmaxf(fmaf(__low2float(u2), sc0, sh0), 0.f);
                float x21 = fmaxf(fmaf(__high2float(u2), sc1, sh1), 0.f);
                float x30 = fmaxf(fmaf(__low2float(u3), sc0, sh0), 0.f);
                float x31 = fmaxf(fmaf(__high2float(u3), sc1, sh1), 0.f);
                a0 = fmaf(x00, w0, a0); a1 = fmaf(x01, w0, a1);
                b0 = fmaf(x10, w1, b0); b1 = fmaf(x11, w1, b1);
                c0 = fmaf(x20, w2, c0); c1 = fmaf(x21, w2, c1);
                e0 = fmaf(x30, w3, e0); e1 = fmaf(x31, w3, e1);
            }
            for (; i < e; i += 2) {
                int r = rows[i];
                float w0 = dinv[r];
                __half2 u = h2[(long)r * 32 + q];
                float x0 = fmaxf(fmaf(__low2float(u), sc0, sh0), 0.f);
                float x1 = fmaxf(fmaf(__high2float(u), sc1, sh1), 0.f);
                a0 = fmaf(x0, w0, a0); a1 = fmaf(x1, w0, a1);
            }
            a0 = (a0 + b0) + (c0 + e0);
            a1 = (a1 + b1) + (c1 + e1);
            a0 += __shfl_xor(a0, 32, 64);
            a1 += __shfl_xor(a1, 32, 64);
            if (!grp) sPw[q] = make_float2(a0 * dc, a1 * dc);
            float z = bd;
#pragma unroll
            for (int j = 0; j < 16; ++j) {
                float4 pv = sPv[j];
                float4 wv = sW4[j * 64 + d];
                z = fmaf(pv.x, wv.x, z); z = fmaf(pv.y, wv.y, z);
                z = fmaf(pv.z, wv.z, z); z = fmaf(pv.w, wv.w, z);
            }
            Z[(long)node * DD + d] = __float2half(z);
            sumz += z; sumq += z * z;
        }
    }
    __syncthreads();
    rs[tid] = sumz; __syncthreads();
    if (tid < 64) atomicAdd(&ostats[tid], rs[tid] + rs[tid + 64] + rs[tid + 128] + rs[tid + 192]);
    __syncthreads();
    rs[tid] = sumq; __syncthreads();
    if (tid < 64) atomicAdd(&ostats[64 + tid], rs[tid] + rs[tid + 64] + rs[tid + 128] + rs[tid + 192]);
}

// ================= conv1-l0: half2 gather from normalized fp16 table (L2-resident) =================
__global__ __launch_bounds__(256) void gcn_tab_fused_k(
    const __half* __restrict__ Tn, const int* __restrict__ xidx,
    const int2* __restrict__ offs, const int* __restrict__ rows,
    const float* __restrict__ dinv,
    const float* __restrict__ W, const float* __restrict__ bias,
    __half* __restrict__ Z, float* __restrict__ ostats, int n)
{
    __shared__ float4 sW4[1024];
    __shared__ float sP[256];
    __shared__ float rs[256];
    int tid = threadIdx.x;
    load_W4(W, sW4, tid);
    int wr = tid >> 6, d = tid & 63;
    int q = tid & 31, grp = (tid >> 5) & 1;
    float bd = bias[d];
    float sumz = 0.f, sumq = 0.f;
    const __half2* t2 = (const __half2*)Tn;
    float2* sPw = (float2*)(sP + wr * 64);
    const float4* sPv = (const float4*)(sP + wr * 64);
    int ngrp = (n + 3) >> 2;
    __syncthreads();
    for (int g = blockIdx.x; g < ngrp; g += gridDim.x) {
        int node = g * 4 + wr;
        if (node < n) {
            int2 se = offs[node];
            int s = se.x, e = se.y;
            float dc = dinv[node];
            float a0 = 0.f, a1 = 0.f, b0 = 0.f, b1 = 0.f;
            float c0 = 0.f, c1 = 0.f, e0 = 0.f, e1 = 0.f;
            if (!grp) {
                __half2 u = t2[(long)xidx[node] * 32 + q];
                a0 = __low2float(u) * dc; a1 = __high2float(u) * dc;
            }
            int i = s + grp;
            for (; i + 6 < e; i += 8) {
                int r0 = rows[i], r1 = rows[i + 2], r2 = rows[i + 4], r3 = rows[i + 6];
                float w0 = dinv[r0], w1 = dinv[r1], w2 = dinv[r2], w3 = dinv[r3];
                __half2 u0 = t2[(long)xidx[r0] * 32 + q];
                __half2 u1 = t2[(long)xidx[r1] * 32 + q];
                __half2 u2 = t2[(long)xidx[r2] * 32 + q];
                __half2 u3 = t2[(long)xidx[r3] * 32 + q];
                a0 = fmaf(__low2float(u0), w0, a0); a1 = fmaf(__high2float(u0), w0, a1);
                b0 = fmaf(__low2float(u1), w1, b0); b1 = fmaf(__high2float(u1), w1, b1);
                c0 = fmaf(__low2float(u2), w2, c0); c1 = fmaf(__high2float(u2), w2, c1);
                e0 = fmaf(__low2float(u3), w3, e0); e1 = fmaf(__high2float(u3), w3, e1);
            }
            for (; i < e; i += 2) {
                int r = rows[i];
                float w0 = dinv[r];
                __half2 u = t2[(long)xidx[r] * 32 + q];
                a0 = fmaf(__low2float(u), w0, a0); a1 = fmaf(__high2float(u), w0, a1);
            }
            a0 = (a0 + b0) + (c0 + e0);
            a1 = (a1 + b1) + (c1 + e1);
            a0 += __shfl_xor(a0, 32, 64);
            a1 += __shfl_xor(a1, 32, 64);
            if (!grp) sPw[q] = make_float2(a0 * dc, a1 * dc);
            float z = bd;
#pragma unroll
            for (int j = 0; j < 16; ++j) {
                float4 pv = sPv[j];
                float4 wv = sW4[j * 64 + d];
                z = fmaf(pv.x, wv.x, z); z = fmaf(pv.y, wv.y, z);
                z = fmaf(pv.z, wv.z, z); z = fmaf(pv.w, wv.w, z);
            }
            Z[(long)node * DD + d] = __float2half(z);
            sumz += z; sumq += z * z;
        }
    }
    __syncthreads();
    rs[tid] = sumz; __syncthreads();
    if (tid < 64) atomicAdd(&ostats[tid], rs[tid] + rs[tid + 64] + rs[tid + 128] + rs[tid + 192]);
    __syncthreads();
    rs[tid] = sumq; __syncthreads();
    if (tid < 64) atomicAdd(&ostats[64 + tid], rs[tid] + rs[tid + 64] + rs[tid + 128] + rs[tid + 192]);
}

// ================= link-pair product: GN+relu on reads, writes TWO pre-scaled copies =================
__global__ __launch_bounds__(256) void pair_norm_mul_k(
    const __half* __restrict__ Z2, const int* __restrict__ pos,
    const float* __restrict__ stats, const float* __restrict__ gw,
    const float* __restrict__ gb, const float* __restrict__ gms,
    const float* __restrict__ dinvA, const float* __restrict__ dinvB,
    __half* __restrict__ ha, __half* __restrict__ hb)
{
    int tid = threadIdx.x, wr = tid >> 6, d = tid & 63;
    int idx = blockIdx.x * 4 + wr;
    if (idx >= MMn) return;
    float sc, sh;
    gn_coef(stats, gw, gb, gms, (float)NN, d, sc, sh);
    int p0 = pos[2 * idx], p1 = pos[2 * idx + 1];
    float v0 = fmaxf(fmaf(__half2float(Z2[(long)p0 * DD + d]), sc, sh), 0.f);
    float v1 = fmaxf(fmaf(__half2float(Z2[(long)p1 * DD + d]), sc, sh), 0.f);
    float v = v0 * v1;
    ha[(long)idx * DD + d] = __float2half(v * dinvA[idx]);
    hb[(long)idx * DD + d] = __float2half(v * dinvB[idx]);
}

// ================= dual-branch GN+relu+add -> two pre-scaled copies =================
__global__ __launch_bounds__(256) void dualadd_k(
    const __half2* __restrict__ Za, const __half2* __restrict__ Zb,
    const float* __restrict__ stA, const float* __restrict__ wA, const float* __restrict__ bA, const float* __restrict__ msA,
    const float* __restrict__ stB, const float* __restrict__ wB, const float* __restrict__ bB, const float* __restrict__ msB,
    const float* __restrict__ dinvA, const float* __restrict__ dinvB,
    __half2* __restrict__ ha, __half2* __restrict__ hb)
{
    const long nu = (long)MMn * 32;
    int tid = threadIdx.x;
    int d0 = (2 * tid) & 63;
    float scA0, shA0, scA1, shA1, scB0, shB0, scB1, shB1;
    gn_coef(stA, wA, bA, msA, (float)MMn, d0, scA0, shA0);
    gn_coef(stA, wA, bA, msA, (float)MMn, d0 + 1, scA1, shA1);
    gn_coef(stB, wB, bB, msB, (float)MMn, d0, scB0, shB0);
    gn_coef(stB, wB, bB, msB, (float)MMn, d0 + 1, scB1, shB1);
    for (long i = (long)blockIdx.x * 256 + tid; i < nu; i += (long)gridDim.x * 256) {
        __half2 ua = Za[i], ub = Zb[i];
        float a0 = __low2float(ua), a1 = __high2float(ua);
        float c0 = __low2float(ub), c1 = __high2float(ub);
        float o0 = fmaxf(fmaf(a0, scA0, shA0), 0.f) + fmaxf(fmaf(c0, scB0, shB0), 0.f);
        float o1 = fmaxf(fmaf(a1, scA1, shA1), 0.f) + fmaxf(fmaf(c1, scB1, shB1), 0.f);
        int node = (int)(i >> 5);
        float wa = dinvA[node], wb = dinvB[node];
        ha[i] = __halves2half2(__float2half(o0 * wa), __float2half(o1 * wa));
        hb[i] = __halves2half2(__float2half(o0 * wb), __float2half(o1 * wb));
    }
}

// ================= final: dual GN+relu+add on reads, pair product, dot predW =================
__global__ __launch_bounds__(256) void final_fused_k(
    const __half* __restrict__ Za, const __half* __restrict__ Zb,
    const int* __restrict__ pos2,
    const float* __restrict__ stA, const float* __restrict__ wA, const float* __restrict__ bA, const float* __restrict__ msA,
    const float* __restrict__ stB, const float* __restrict__ wB, const float* __restrict__ bB, const float* __restrict__ msB,
    const float* __restrict__ pw, const float* __restrict__ pb,
    float* __restrict__ out, int nout)
{
    int tid = threadIdx.x, wr = tid >> 6, d = tid & 63;
    int i = blockIdx.x * 4 + wr;
    if (i >= nout) return;
    float scA, shA, scB, shB;
    gn_coef(stA, wA, bA, msA, (float)MMn, d, scA, shA);
    gn_coef(stB, wB, bB, msB, (float)MMn, d, scB, shB);
    int p0 = pos2[2 * i], p1 = pos2[2 * i + 1];
    float v0 = fmaxf(fmaf(__half2float(Za[(long)p0 * DD + d]), scA, shA), 0.f)
             + fmaxf(fmaf(__half2float(Zb[(long)p0 * DD + d]), scB, shB), 0.f);
    float v1 = fmaxf(fmaf(__half2float(Za[(long)p1 * DD + d]), scA, shA), 0.f)
             + fmaxf(fmaf(__half2float(Zb[(long)p1 * DD + d]), scB, shB), 0.f);
    float v = v0 * v1 * pw[d];
#pragma unroll
    for (int o = 32; o > 0; o >>= 1) v += __shfl_down(v, o, 64);
    if (d == 0) out[i] = v + pb[0];
}

extern "C" void kernel_launch(void* const* d_in, const int* in_sizes, int n_in,
                              void* d_out, int out_size, void* d_ws, size_t ws_size,
                              hipStream_t stream) {
    const int* x      = (const int*)d_in[0];
    const int* edge1  = (const int*)d_in[2];
    const int* edge2  = (const int*)d_in[3];
    const int* pos1   = (const int*)d_in[5];
    const int* pos2   = (const int*)d_in[6];
    const float* emb  = (const float*)d_in[7];
    const float* egw  = (const float*)d_in[8];
    const float* egb  = (const float*)d_in[9];
    const float* egm  = (const float*)d_in[10];
    const float* c1W  = (const float*)d_in[11];
    const float* c1b  = (const float*)d_in[12];
    const float* c1gw = (const float*)d_in[13];
    const float* c1gb = (const float*)d_in[14];
    const float* c1gm = (const float*)d_in[15];
    const float* c2W  = (const float*)d_in[16];
    const float* c2b  = (const float*)d_in[17];
    const float* c2gw = (const float*)d_in[18];
    const float* c2gb = (const float*)d_in[19];
    const float* c2gm = (const float*)d_in[20];
    const float* c2rW  = (const float*)d_in[21];
    const float* c2rb  = (const float*)d_in[22];
    const float* c2rgw = (const float*)d_in[23];
    const float* c2rgb = (const float*)d_in[24];
    const float* c2rgm = (const float*)d_in[25];
    const float* predW = (const float*)d_in[26];
    const float* predb = (const float*)d_in[27];
    float* out = (float*)d_out;
    const int NV = 1001;   // emb table rows (MAXX+1)

    // ---- workspace layout (~182 MB) ----
    char* p = (char*)d_ws;
    const long SZH = (long)MMn * DD;  // elements per fp16 node buffer
    __half* BA = (__half*)p; p += SZH * 2;
    __half* BB = (__half*)p; p += SZH * 2;
    __half* BC = (__half*)p; p += SZH * 2;
    __half* BD = (__half*)p; p += SZH * 2;
    int* stg   = (int*)p;   p += (long)NB2 * CAP2 * 4;      // 19.2 MB (>= NB1*CAP1*4 = 16 MB)
    int* rows1 = (int*)p; p += (long)NB1 * CAP1 * 4;        // 16 MB
    int* rowsA = (int*)p; p += (long)NB2 * CAP2 * 4;        // 19.2 MB
    int* rowsB = (int*)p; p += (long)NB2 * CAP2 * 4;        // 19.2 MB
    int2* offs1 = (int2*)p; p += (long)NN * 8;
    int2* offsA = (int2*)p; p += (long)MMn * 8;
    int2* offsB = (int2*)p; p += (long)MMn * 8;
    float* dinv1  = (float*)p; p += (long)NN * 4;
    float* dinv2  = (float*)p; p += (long)MMn * 4;
    float* dinv2r = (float*)p; p += (long)MMn * 4;
    int* gcur1 = (int*)p; p += 2048 * 4;
    int* gcurA = (int*)p; p += 4096 * 4;
    int* gcurB = (int*)p; p += 4096 * 4;
    int* freq = (int*)p; p += 1024 * 4;
    float* stats = (float*)p; p += 7 * 128 * 4;   // slots 0..6
    __half* Tn = (__half*)p; p += (long)NV * DD * 2;
    if ((size_t)(p - (char*)d_ws) > ws_size) return;

    // ---- zero freq + stats ----
    fill_i32_k<<<4, 256, 0, stream>>>(freq, 0, 1024);
    fill_f32_k<<<1, 256, 0, stream>>>(stats, 0.f, 7 * 128);

    // ---- emb-frequency histogram + table norm ----
    histx_k<<<cdiv_l(NN, 256), 256, 0, stream>>>(x, NN, freq);
    tabstats_k<<<1, 256, 0, stream>>>(emb, freq, NV, stats);
    tnorm_k<<<cdiv_l((long)NV * DD, 256), 256, 0, stream>>>(emb, stats, egw, egb, egm, Tn, NV);

    // ---- CSR build, atomic-light (g1, then g2 fwd, then g2 rev; stg reused serially) ----
    ginit_k<<<cdiv_l(NB1, 256), 256, 0, stream>>>(gcur1, NB1, CAP1);
    stage_one_k<<<NBLK, 256, 0, stream>>>(edge1 + NE1, edge1, NE1, gcur1, stg, NB1, CAP1);
    fill_one_k<CAP1><<<NB1, 256, 0, stream>>>(stg, gcur1, NN, rows1, offs1, dinv1);

    ginit_k<<<cdiv_l(NB2, 256), 256, 0, stream>>>(gcurA, NB2, CAP2);
    stage_one_k<<<NBLK, 256, 0, stream>>>(edge2 + NE2, edge2, NE2, gcurA, stg, NB2, CAP2);
    fill_one_k<CAP2><<<NB2, 256, 0, stream>>>(stg, gcurA, MMn, rowsA, offsA, dinv2);

    ginit_k<<<cdiv_l(NB2, 256), 256, 0, stream>>>(gcurB, NB2, CAP2);
    stage_one_k<<<NBLK, 256, 0, stream>>>(edge2, edge2 + NE2, NE2, gcurB, stg, NB2, CAP2);
    fill_one_k<CAP2><<<NB2, 256, 0, stream>>>(stg, gcurB, MMn, rowsB, offsB, dinv2r);

    // ---- conv1 l0: table-gather + mm -> BB, stats slot1 fused ----
    gcn_tab_fused_k<<<GGRID, 256, 0, stream>>>(Tn, x, offs1, rows1, dinv1, c1W, c1b, BB, stats + 128, NN);

    // ---- conv1 l1: gather(norm+relu) + mm -> BA, stats slot2 fused ----
    gcn_fused_k<<<GGRID, 256, 0, stream>>>(BB, offs1, rows1, dinv1,
        stats + 128, c1gw, c1gb, c1gm, (float)NN, c1W + 4096, c1b + 64, BA, stats + 256, NN);

    // ---- pair product -> BC (=h*dinv2), BD (=h*dinv2r) ----
    pair_norm_mul_k<<<cdiv_l(MMn, 4), 256, 0, stream>>>(BA, pos1,
        stats + 256, c1gw + 64, c1gb + 64, c1gm + 64, dinv2, dinv2r, BC, BD);

    // ---- conv2 l0: pure-sum gathers (stats slots 3,4 fused) ----
    gcn_sum_k<<<GGRID, 256, 0, stream>>>(BC, offsA, rowsA, dinv2, c2W, c2b, BB, stats + 384, MMn);
    gcn_sum_k<<<GGRID, 256, 0, stream>>>(BD, offsB, rowsB, dinv2r, c2rW, c2rb, BA, stats + 512, MMn);
    dualadd_k<<<1024, 256, 0, stream>>>((const __half2*)BB, (const __half2*)BA,
        stats + 384, c2gw, c2gb, c2gm,
        stats + 512, c2rgw, c2rgb, c2rgm,
        dinv2, dinv2r, (__half2*)BC, (__half2*)BD);

    // ---- conv2 l1 (stats slots 5,6 fused) ----
    gcn_sum_k<<<GGRID, 256, 0, stream>>>(BC, offsA, rowsA, dinv2, c2W + 4096, c2b + 64, BB, stats + 640, MMn);
    gcn_sum_k<<<GGRID, 256, 0, stream>>>(BD, offsB, rowsB, dinv2r, c2rW + 4096, c2rb + 64, BA, stats + 768, MMn);

    // ---- final ----
    final_fused_k<<<cdiv_l(out_size, 4), 256, 0, stream>>>(BB, BA, pos2,
        stats + 640, c2gw + 64, c2gb + 64, c2gm + 64,
        stats + 768, c2rgw + 64, c2rgb + 64, c2rgm + 64,
        predW, predb, out, out_size);
}